// Round 23
// baseline (198.357 us; speedup 1.0000x reference)
//
#include <hip/hip_runtime.h>
#include <hip/hip_fp16.h>
#include <math.h>
#include <string.h>

#define VOL   128
#define V2    (VOL*VOL)
#define V3    (VOL*VOL*VOL)
#define NPTS  262144
#define LATD  16
#define BATCH 8
#define FACTORF 64.0f
#define NBINS (VOL*VOL)
#define RZ 8
#define RY 4
#define REG_PER_B ((VOL/RZ)*(VOL/RY))   // 512
#define HALO_Z 13
#define HALO_Y 9
#define NRANGE (HALO_Z*HALO_Y)          // 117
#define FAR_CAP 8192

// ws layout (bytes); total 17.1MB < 18.1MB proven available (R18)
#define WS_HBUF   0u
#define WS_HIST   256u        // 65536
#define WS_START  65792u      // 65792 (NBINS+1 + pad)
#define WS_CURSOR 131584u     // 65536
#define WS_WGSUM  197120u     // 256
#define WS_CTRL   197376u     // 32
#define WS_FARBUF 197408u     // 131072
#define WS_COORDC 328480u     // NPTS*BATCH*8 = 16777216
#define WS_FULL   17105696u

__device__ __forceinline__ float bf16r(float x) {
    unsigned u = __float_as_uint(x);
    u = (u + 0x7fffu + ((u >> 16) & 1u)) & 0xffff0000u;
    return __uint_as_float(u);
}
__device__ __forceinline__ unsigned short f16bits(float v) {
    __half h = __float2half_rn(v);
    unsigned short us; memcpy(&us, &h, 2);
    return us;
}
__device__ __forceinline__ float f16val(unsigned short us) {
    __half h; memcpy(&h, &us, 2);
    return __half2float(h);
}

// SIREN MLP, per-op bf16 (verified round 11).
__global__ void mlp_kernel(const float* __restrict__ x,
                           const float* __restrict__ W0,
                           const float* __restrict__ b0,
                           const float* __restrict__ Wh,
                           const float* __restrict__ bh,
                           float* __restrict__ hout) {
    int b = threadIdx.x;
    if (b >= BATCH) return;
    float xb[LATD];
    #pragma unroll
    for (int i = 0; i < LATD; ++i) xb[i] = bf16r(x[b*LATD + i]);
    float h[8];
    #pragma unroll
    for (int j = 0; j < 8; ++j) {
        float acc = 0.f;
        #pragma unroll
        for (int i = 0; i < LATD; ++i) acc += xb[i] * bf16r(W0[i*8 + j]);
        float t = bf16r(acc);
        t = bf16r(t + bf16r(b0[j]));
        t = bf16r(30.0f * t);
        h[j] = bf16r(sinf(t));
    }
    for (int l = 0; l < 4; ++l) {
        float nh[8];
        #pragma unroll
        for (int j = 0; j < 8; ++j) {
            float acc = 0.f;
            #pragma unroll
            for (int r = 0; r < 8; ++r) acc += h[r] * bf16r(Wh[(l*8 + r)*8 + j]);
            float t = bf16r(acc);
            t = bf16r(t + bf16r(bh[l*8 + j]));
            float s = bf16r(sinf(t));
            nh[j] = bf16r(h[j] + s);
        }
        #pragma unroll
        for (int j = 0; j < 8; ++j) h[j] = nh[j];
    }
    #pragma unroll
    for (int j = 0; j < 8; ++j) hout[b*8 + j] = h[j];
}

__global__ __launch_bounds__(256) void hist_kernel(const int* __restrict__ inds,
                                                   unsigned* __restrict__ hist) {
    int n = blockIdx.x * 256 + threadIdx.x;
    if (n >= NPTS) return;
    atomicAdd(&hist[inds[n*3]*VOL + inds[n*3+1]], 1u);
}

// Multi-block scan over 16384 bins; scanC also fills the cursor copy.
__global__ __launch_bounds__(256) void scanA_kernel(const unsigned* __restrict__ hist,
                                                    unsigned* __restrict__ wgsum) {
    __shared__ unsigned s[256];
    int t = threadIdx.x;
    s[t] = hist[blockIdx.x * 256 + t];
    __syncthreads();
    for (int off = 128; off > 0; off >>= 1) {
        if (t < off) s[t] += s[t + off];
        __syncthreads();
    }
    if (t == 0) wgsum[blockIdx.x] = s[0];
}
__global__ __launch_bounds__(64) void scanB_kernel(unsigned* __restrict__ wgsum,
                                                   unsigned* __restrict__ binstart,
                                                   unsigned* __restrict__ ctrl) {
    if (threadIdx.x == 0) {
        unsigned run = 0;
        for (int i = 0; i < 64; ++i) { unsigned v = wgsum[i]; wgsum[i] = run; run += v; }
        binstart[NBINS] = run;
        ctrl[0] = 0u; ctrl[1] = 0u;
    }
}
__global__ __launch_bounds__(256) void scanC_kernel(const unsigned* __restrict__ hist,
                                                    const unsigned* __restrict__ wgsum,
                                                    unsigned* __restrict__ binstart,
                                                    unsigned* __restrict__ cursor) {
    __shared__ unsigned s[256];
    int t = threadIdx.x;
    int idx = blockIdx.x * 256 + t;
    unsigned h = hist[idx];
    s[t] = h; __syncthreads();
    for (int off = 1; off < 256; off <<= 1) {
        unsigned v = (t >= off) ? s[t - off] : 0u;
        __syncthreads();
        s[t] += v;
        __syncthreads();
    }
    unsigned excl = s[t] - h + wgsum[blockIdx.x];
    binstart[idx] = excl;
    cursor[idx]   = excl;
}

// Per point: slot via atomic cursor (no rank pass); 8B quantized entries into
// per-batch bin-sorted planes. near window +-2 both axes; far -> exact float4
// sidebuf with cz biased by 256*b; sentinel ey=0xFFFF in the entry.
__global__ __launch_bounds__(256) void coords_kernel(
    const float* __restrict__ Wf, const float* __restrict__ bfv_g,
    const float* __restrict__ rv, const int* __restrict__ inds,
    const float* __restrict__ hbuf, unsigned* __restrict__ cursor,
    unsigned* __restrict__ ctrl, float4* __restrict__ farbuf,
    ushort4* __restrict__ coords_c)
{
    __shared__ float hs[64];
    if (threadIdx.x < 64) hs[threadIdx.x] = hbuf[threadIdx.x];
    __syncthreads();
    int n = blockIdx.x * 256 + threadIdx.x;
    if (n >= NPTS) return;
    int iz = inds[n*3], iy = inds[n*3+1], ix = inds[n*3+2];
    float cnx = ((float)ix - FACTORF) / FACTORF;
    float cny = ((float)iy - FACTORF) / FACTORF;
    float cnz = ((float)iz - FACTORF) / FACTORF;
    float val0 = rv[n];
    float4 bfv = ((const float4*)bfv_g)[n];
    float4 wf[8];
    #pragma unroll
    for (int r = 0; r < 8; ++r)
        wf[r] = ((const float4*)(Wf + (size_t)r * 4 * NPTS))[n];
    unsigned pos = atomicAdd(&cursor[iz*VOL + iy], 1u);
    #pragma unroll
    for (int b = 0; b < BATCH; ++b) {
        float o0 = bfv.x, o1 = bfv.y, o2 = bfv.z, o3 = bfv.w;
        #pragma unroll
        for (int r = 0; r < 8; ++r) {
            float hv = hs[b*8 + r];
            o0 = fmaf(hv, wf[r].x, o0);
            o1 = fmaf(hv, wf[r].y, o1);
            o2 = fmaf(hv, wf[r].z, o2);
            o3 = fmaf(hv, wf[r].w, o3);
        }
        float cx = FACTORF * (cnx + o0) + FACTORF;
        float cy = FACTORF * (cny + o1) + FACTORF;
        float cz = FACTORF * (cnz + o2) + FACTORF;
        float val = val0 + o3;
        int bz = (int)floorf(cz), by = (int)floorf(cy);
        bool nearzy = ((unsigned)(bz - iz + 2) <= 4u) &&
                      ((unsigned)(by - iy + 2) <= 4u);
        ushort4 e;
        if (nearzy) {
            e.x = (unsigned short)fminf(fmaxf(fmaf(cx + 8.f, 256.f, 0.5f), 0.f), 65535.f);
            e.y = (unsigned short)fminf(fmaf(cy - (float)iy + 2.f, 8192.f, 0.5f), 40959.f);
            e.z = (unsigned short)fminf(fmaf(cz - (float)iz + 2.f, 8192.f, 0.5f), 40959.f);
            e.w = f16bits(val);
        } else {
            e.x = 0; e.y = 0xFFFFu; e.z = 0; e.w = 0;
            unsigned fp = atomicAdd(&ctrl[0], 1u);
            if (fp < FAR_CAP)
                farbuf[fp] = make_float4(cx, cy, cz + 256.0f * (float)b, val);
        }
        coords_c[(size_t)b * NPTS + pos] = e;
    }
}

// One wg = (batch, RZ x RY x 128 region): R16's proven structure with 8B
// entries. Per-bin ranges (117) carry (piz,piy); serial cursor; 8-deep ILP.
__global__ __launch_bounds__(256) void region_kernel(
    const ushort4* __restrict__ coords_c,
    const unsigned* __restrict__ binstart, float* __restrict__ out)
{
    __shared__ float tile[RZ*RY*VOL];   // 16 KB
    __shared__ unsigned rstart[NRANGE];
    __shared__ unsigned rcum[NRANGE+1];
    __shared__ short rpz[NRANGE], rpy[NRANGE];
    int tid = threadIdx.x;
    int b   = blockIdx.x >> 9;
    int rid = blockIdx.x & 511;
    int z0 = (rid >> 5) * RZ, y0 = (rid & 31) * RY;

    for (int i = tid; i < RZ*RY*VOL; i += 256) tile[i] = 0.f;

    if (tid < NRANGE) {
        int zi = tid / HALO_Y, yi = tid - zi * HALO_Y;
        int zz = (z0 - 3 + zi) & (VOL-1);
        int yy = (y0 - 3 + yi) & (VOL-1);
        int base = zz * VOL + yy;
        unsigned s = binstart[base];
        rstart[tid] = s;
        rpz[tid] = (short)zz; rpy[tid] = (short)yy;
        rcum[tid+1] = binstart[base+1] - s;
    }
    if (tid == 0) rcum[0] = 0u;
    __syncthreads();
    for (int off = 1; off < NRANGE; off <<= 1) {
        unsigned v = 0u;
        if (tid < NRANGE && tid >= off) v = rcum[tid+1-off];
        __syncthreads();
        if (tid < NRANGE && tid >= off) rcum[tid+1] += v;
        __syncthreads();
    }
    unsigned total = rcum[NRANGE];

    const int ox[8] = {0,1,0,0,0,1,1,1};
    const int oy[8] = {0,0,1,0,1,0,1,1};
    const int oz[8] = {0,0,0,1,1,1,0,1};
    const ushort4* cb = coords_c + (size_t)b * NPTS;

    int r = 0;
    for (unsigned f = tid; f < total; f += 2048u) {
        ushort4 e[8]; int pz[8], py[8]; bool v[8];
        #pragma unroll
        for (int u = 0; u < 8; ++u) {
            unsigned fu = f + (unsigned)u * 256u;
            v[u] = fu < total;
            if (v[u]) {
                while (fu >= rcum[r+1]) ++r;
                unsigned j = rstart[r] + (fu - rcum[r]);
                e[u] = cb[j];
                pz[u] = rpz[r]; py[u] = rpy[r];
            }
        }
        #pragma unroll
        for (int u = 0; u < 8; ++u) {
            if (!v[u] || e[u].y == 0xFFFFu) continue;
            int piz = pz[u], piy = py[u];
            float cx = (float)e[u].x * (1.f/256.f) - 8.f;
            float cy = (float)piy + (float)e[u].y * (1.f/8192.f) - 2.f;
            float cz = (float)piz + (float)e[u].z * (1.f/8192.f) - 2.f;
            float val = f16val(e[u].w);
            float fxf = floorf(cx), fyf = floorf(cy), fzf = floorf(cz);
            int bx = (int)fxf, by = (int)fyf, bz = (int)fzf;
            float fx = cx - fxf, fy = cy - fyf, fz = cz - fzf;
            float gx = 1.f - fx, gy = 1.f - fy, gz = 1.f - fz;
            float w[8] = {gx*gy*gz, fx*gy*gz, gx*fy*gz, gx*gy*fz,
                          gx*fy*fz, fx*gy*fz, fx*fy*gz, fx*fy*fz};
            #pragma unroll
            for (int o = 0; o < 8; ++o) {
                int Z = (bz + oz[o]) & 127, dz = Z - z0;
                if ((unsigned)dz >= RZ) continue;
                int Y = (by + oy[o]) & 127, dy = Y - y0;
                if ((unsigned)dy >= RY) continue;
                int X = (bx + ox[o]) & 127;
                atomicAdd(&tile[(dz << 9) + (dy << 7) + X], val * w[o]);
            }
        }
    }
    __syncthreads();
    size_t ob = (size_t)b * V3;
    for (int i = tid; i < RZ*RY*VOL; i += 256) {
        int lz = i >> 9, ly = (i >> 7) & (RY-1), lx = i & 127;
        out[ob + (size_t)(z0+lz)*V2 + (y0+ly)*VOL + lx] = tile[i];
    }
}

// Far entries: cz carries 256*b bias (exact float path).
__global__ __launch_bounds__(256) void far_kernel(
    const unsigned* __restrict__ ctrl, const float4* __restrict__ farbuf,
    float* __restrict__ out)
{
    unsigned cnt = ctrl[0];
    if (cnt > FAR_CAP) cnt = FAR_CAP;
    const int ox[8] = {0,1,0,0,0,1,1,1};
    const int oy[8] = {0,0,1,0,1,0,1,1};
    const int oz[8] = {0,0,0,1,1,1,0,1};
    for (unsigned idx = blockIdx.x * 256 + threadIdx.x; idx < cnt;
         idx += gridDim.x * 256) {
        float4 c = farbuf[idx];
        int b = (int)floorf((c.z + 8.0f) * (1.0f/256.0f));
        float cz = c.z - 256.0f * (float)b;
        float fxf = floorf(c.x), fyf = floorf(c.y), fzf = floorf(cz);
        int bx = (int)fxf, by = (int)fyf, bz = (int)fzf;
        float fx = c.x - fxf, fy = c.y - fyf, fz = cz - fzf;
        float gx = 1.f - fx, gy = 1.f - fy, gz = 1.f - fz;
        float val = c.w;
        float w[8] = {gx*gy*gz, fx*gy*gz, gx*fy*gz, gx*gy*fz,
                      gx*fy*fz, fx*gy*fz, fx*fy*gz, fx*fy*fz};
        float* ob = out + (size_t)b * V3;
        #pragma unroll
        for (int o = 0; o < 8; ++o) {
            int Z = (bz + oz[o]) & (VOL-1);
            int Y = (by + oy[o]) & (VOL-1);
            int X = (bx + ox[o]) & (VOL-1);
            atomicAdd(ob + (size_t)Z*V2 + Y*VOL + X, val * w[o]);
        }
    }
}

// Fallback (round-11 verified path) if workspace too small.
__global__ __launch_bounds__(256) void scatter_fallback(
    const float* __restrict__ Wf, const float* __restrict__ bfv_g,
    const float* __restrict__ rv, const int* __restrict__ inds,
    const float* __restrict__ hbuf, float* __restrict__ out)
{
    __shared__ float hs[BATCH*8];
    if (threadIdx.x < BATCH*8) hs[threadIdx.x] = hbuf[threadIdx.x];
    __syncthreads();
    int n = blockIdx.x * blockDim.x + threadIdx.x;
    if (n >= NPTS) return;
    int iz = inds[n*3 + 0], iy = inds[n*3 + 1], ix = inds[n*3 + 2];
    float cnx = ((float)ix - FACTORF) / FACTORF;
    float cny = ((float)iy - FACTORF) / FACTORF;
    float cnz = ((float)iz - FACTORF) / FACTORF;
    float val0 = rv[n];
    float4 bfv = ((const float4*)bfv_g)[n];
    float4 wf[8];
    #pragma unroll
    for (int r = 0; r < 8; ++r)
        wf[r] = ((const float4*)(Wf + (size_t)r * 4 * NPTS))[n];
    static const int offs[8][3] = {{0,0,0},{1,0,0},{0,1,0},{0,0,1},
                                   {0,1,1},{1,0,1},{1,1,0},{1,1,1}};
    #pragma unroll
    for (int b = 0; b < BATCH; ++b) {
        float o0 = bfv.x, o1 = bfv.y, o2 = bfv.z, o3 = bfv.w;
        #pragma unroll
        for (int r = 0; r < 8; ++r) {
            float hv = hs[b*8 + r];
            o0 = fmaf(hv, wf[r].x, o0);
            o1 = fmaf(hv, wf[r].y, o1);
            o2 = fmaf(hv, wf[r].z, o2);
            o3 = fmaf(hv, wf[r].w, o3);
        }
        float cx = FACTORF * (cnx + o0) + FACTORF;
        float cy = FACTORF * (cny + o1) + FACTORF;
        float cz = FACTORF * (cnz + o2) + FACTORF;
        float val = val0 + o3;
        float fxf = floorf(cx), fyf = floorf(cy), fzf = floorf(cz);
        int bx = (int)fxf, by = (int)fyf, bz = (int)fzf;
        float fx = cx - fxf, fy = cy - fyf, fz = cz - fzf;
        float gx = 1.f - fx, gy = 1.f - fy, gz = 1.f - fz;
        float w[8] = {gx*gy*gz, fx*gy*gz, gx*fy*gz, gx*gy*fz,
                      gx*fy*fz, fx*gy*fz, fx*fy*gz, fx*fy*fz};
        float* ob = out + (size_t)b * V3;
        #pragma unroll
        for (int o = 0; o < 8; ++o) {
            int X = (bx + offs[o][0]) & (VOL-1);
            int Y = (by + offs[o][1]) & (VOL-1);
            int Z = (bz + offs[o][2]) & (VOL-1);
            atomicAdd(ob + (size_t)Z*V2 + Y*VOL + X, val * w[o]);
        }
    }
}

extern "C" void kernel_launch(void* const* d_in, const int* in_sizes, int n_in,
                              void* d_out, int out_size, void* d_ws, size_t ws_size,
                              hipStream_t stream) {
    const float* x    = (const float*)d_in[0];
    const float* W0   = (const float*)d_in[1];
    const float* b0   = (const float*)d_in[2];
    const float* Wh   = (const float*)d_in[3];
    const float* bh   = (const float*)d_in[4];
    const float* Wf   = (const float*)d_in[5];
    const float* bf   = (const float*)d_in[6];
    const float* rv   = (const float*)d_in[7];
    const int*   inds = (const int*)d_in[8];
    float* out = (float*)d_out;
    char*  ws  = (char*)d_ws;

    float*    hbuf     = (float*)(ws + WS_HBUF);
    unsigned* hist     = (unsigned*)(ws + WS_HIST);
    unsigned* binstart = (unsigned*)(ws + WS_START);
    unsigned* cursor   = (unsigned*)(ws + WS_CURSOR);
    unsigned* wgsum    = (unsigned*)(ws + WS_WGSUM);
    unsigned* ctrl     = (unsigned*)(ws + WS_CTRL);
    float4*   farbuf   = (float4*)(ws + WS_FARBUF);
    ushort4*  coords_c = (ushort4*)(ws + WS_COORDC);

    mlp_kernel<<<1, 64, 0, stream>>>(x, W0, b0, Wh, bh, hbuf);

    if (ws_size >= (size_t)WS_FULL) {
        hipMemsetAsync(hist, 0, NBINS*4, stream);
        hist_kernel<<<NPTS/256, 256, 0, stream>>>(inds, hist);
        scanA_kernel<<<64, 256, 0, stream>>>(hist, wgsum);
        scanB_kernel<<<1, 64, 0, stream>>>(wgsum, binstart, ctrl);
        scanC_kernel<<<64, 256, 0, stream>>>(hist, wgsum, binstart, cursor);
        coords_kernel<<<NPTS/256, 256, 0, stream>>>(Wf, bf, rv, inds, hbuf,
                                                    cursor, ctrl, farbuf, coords_c);
        region_kernel<<<REG_PER_B*BATCH, 256, 0, stream>>>(coords_c, binstart, out);
        far_kernel<<<8, 256, 0, stream>>>(ctrl, farbuf, out);
    } else {
        hipMemsetAsync(d_out, 0, (size_t)out_size * sizeof(float), stream);
        scatter_fallback<<<NPTS/256, 256, 0, stream>>>(Wf, bf, rv, inds, hbuf, out);
    }
}

// Round 24
// 179.452 us; speedup vs baseline: 1.1053x; 1.1053x over previous
//
#include <hip/hip_runtime.h>
#include <math.h>

#define VOL   128
#define V2    (VOL*VOL)
#define V3    (VOL*VOL*VOL)
#define NPTS  262144
#define LATD  16
#define BATCH 8
#define FACTORF 64.0f
#define NBINS (VOL*VOL)
#define RZ 8
#define RY 4
#define REG_PER_B ((VOL/RZ)*(VOL/RY))   // 512
#define FAR_CAP 8128

// ws layout (bytes) -- within the 35.3MB proven available (R16)
#define WS_HBUF    0u
#define WS_HIST    256u
#define WS_START   65792u
#define WS_RANK    131344u
#define WS_KEYS    1179920u
#define WS_CTRL    1704208u
#define WS_WGSUM   1704240u
#define WS_FARLIST 1704496u
#define WS_COORDS  1737008u
#define WS_FULL    35291440u

__device__ __forceinline__ float bf16r(float x) {
    unsigned u = __float_as_uint(x);
    u = (u + 0x7fffu + ((u >> 16) & 1u)) & 0xffff0000u;
    return __uint_as_float(u);
}

// SIREN MLP, per-op bf16 (verified round 11).
__global__ void mlp_kernel(const float* __restrict__ x,
                           const float* __restrict__ W0,
                           const float* __restrict__ b0,
                           const float* __restrict__ Wh,
                           const float* __restrict__ bh,
                           float* __restrict__ hout) {
    int b = threadIdx.x;
    if (b >= BATCH) return;
    float xb[LATD];
    #pragma unroll
    for (int i = 0; i < LATD; ++i) xb[i] = bf16r(x[b*LATD + i]);
    float h[8];
    #pragma unroll
    for (int j = 0; j < 8; ++j) {
        float acc = 0.f;
        #pragma unroll
        for (int i = 0; i < LATD; ++i) acc += xb[i] * bf16r(W0[i*8 + j]);
        float t = bf16r(acc);
        t = bf16r(t + bf16r(b0[j]));
        t = bf16r(30.0f * t);
        h[j] = bf16r(sinf(t));
    }
    for (int l = 0; l < 4; ++l) {
        float nh[8];
        #pragma unroll
        for (int j = 0; j < 8; ++j) {
            float acc = 0.f;
            #pragma unroll
            for (int r = 0; r < 8; ++r) acc += h[r] * bf16r(Wh[(l*8 + r)*8 + j]);
            float t = bf16r(acc);
            t = bf16r(t + bf16r(bh[l*8 + j]));
            float s = bf16r(sinf(t));
            nh[j] = bf16r(h[j] + s);
        }
        #pragma unroll
        for (int j = 0; j < 8; ++j) h[j] = nh[j];
    }
    #pragma unroll
    for (int j = 0; j < 8; ++j) hout[b*8 + j] = h[j];
}

// Histogram of source bins + within-bin rank (fused).
__global__ __launch_bounds__(256) void hist_rank_kernel(const int* __restrict__ inds,
                                                        unsigned* __restrict__ hist,
                                                        unsigned* __restrict__ rank) {
    int n = blockIdx.x * 256 + threadIdx.x;
    if (n >= NPTS) return;
    rank[n] = atomicAdd(&hist[inds[n*3]*VOL + inds[n*3+1]], 1u);
}

// Multi-block scan over 16384 bins.
__global__ __launch_bounds__(256) void scanA_kernel(const unsigned* __restrict__ hist,
                                                    unsigned* __restrict__ wgsum) {
    __shared__ unsigned s[256];
    int t = threadIdx.x;
    s[t] = hist[blockIdx.x * 256 + t];
    __syncthreads();
    for (int off = 128; off > 0; off >>= 1) {
        if (t < off) s[t] += s[t + off];
        __syncthreads();
    }
    if (t == 0) wgsum[blockIdx.x] = s[0];
}
__global__ __launch_bounds__(64) void scanB_kernel(unsigned* __restrict__ wgsum,
                                                   unsigned* __restrict__ binstart,
                                                   unsigned* __restrict__ ctrl) {
    if (threadIdx.x == 0) {
        unsigned run = 0;
        for (int i = 0; i < 64; ++i) { unsigned v = wgsum[i]; wgsum[i] = run; run += v; }
        binstart[NBINS] = run;
        ctrl[0] = 0u; ctrl[1] = 0u;
    }
}
__global__ __launch_bounds__(256) void scanC_kernel(const unsigned* __restrict__ hist,
                                                    const unsigned* __restrict__ wgsum,
                                                    unsigned* __restrict__ binstart) {
    __shared__ unsigned s[256];
    int t = threadIdx.x;
    int idx = blockIdx.x * 256 + t;
    unsigned h = hist[idx];
    s[t] = h; __syncthreads();
    for (int off = 1; off < 256; off <<= 1) {
        unsigned v = (t >= off) ? s[t - off] : 0u;
        __syncthreads();
        s[t] += v;
        __syncthreads();
    }
    binstart[idx] = s[t] - h + wgsum[blockIdx.x];
}

// Per point: coords for all 8 batches into bin-sorted planes; keys; far det.
__global__ __launch_bounds__(256) void coords_kernel(
    const float* __restrict__ Wf, const float* __restrict__ bfv_g,
    const float* __restrict__ rv, const int* __restrict__ inds,
    const float* __restrict__ hbuf, const unsigned* __restrict__ binstart,
    const unsigned* __restrict__ rank, unsigned short* __restrict__ keys,
    unsigned* __restrict__ ctrl, unsigned* __restrict__ farlist,
    float4* __restrict__ coords_s)
{
    __shared__ float hs[64];
    if (threadIdx.x < 64) hs[threadIdx.x] = hbuf[threadIdx.x];
    __syncthreads();
    int n = blockIdx.x * 256 + threadIdx.x;
    if (n >= NPTS) return;
    int iz = inds[n*3], iy = inds[n*3+1], ix = inds[n*3+2];
    float cnx = ((float)ix - FACTORF) / FACTORF;
    float cny = ((float)iy - FACTORF) / FACTORF;
    float cnz = ((float)iz - FACTORF) / FACTORF;
    float val0 = rv[n];
    float4 bfv = ((const float4*)bfv_g)[n];
    float4 wf[8];
    #pragma unroll
    for (int r = 0; r < 8; ++r)
        wf[r] = ((const float4*)(Wf + (size_t)r * 4 * NPTS))[n];
    unsigned pos = binstart[iz*VOL + iy] + rank[n];
    keys[pos] = (unsigned short)((iz << 7) | iy);
    #pragma unroll
    for (int b = 0; b < BATCH; ++b) {
        float o0 = bfv.x, o1 = bfv.y, o2 = bfv.z, o3 = bfv.w;
        #pragma unroll
        for (int r = 0; r < 8; ++r) {
            float hv = hs[b*8 + r];
            o0 = fmaf(hv, wf[r].x, o0);
            o1 = fmaf(hv, wf[r].y, o1);
            o2 = fmaf(hv, wf[r].z, o2);
            o3 = fmaf(hv, wf[r].w, o3);
        }
        float4 c;
        c.x = FACTORF * (cnx + o0) + FACTORF;
        c.y = FACTORF * (cny + o1) + FACTORF;
        c.z = FACTORF * (cnz + o2) + FACTORF;
        c.w = val0 + o3;
        coords_s[(size_t)b * NPTS + pos] = c;
        int bz = (int)floorf(c.z), by = (int)floorf(c.y);
        bool nearzy = ((unsigned)(bz - iz + 2) <= 4u) &&
                      ((unsigned)(by - iy + 2) <= 4u);
        if (!nearzy) {
            unsigned fp = atomicAdd(&ctrl[0], 1u);
            if (fp < FAR_CAP) farlist[fp] = (pos << 3) | (unsigned)b;
        }
    }
}

// One wg = (batch, RZ x RY x 128 region). R16's 26-flat-range structure,
// but gather SPLIT into address phase (cursor walk, LDS-only) then 8
// back-to-back independent global loads -- restores true 8-deep memory ILP.
__global__ __launch_bounds__(256) void region_kernel(
    const float4* __restrict__ coords_s, const unsigned short* __restrict__ keys,
    const unsigned* __restrict__ binstart, float* __restrict__ out)
{
    __shared__ float tile[RZ*RY*VOL];   // 16 KB
    __shared__ unsigned rstart[26], rcnt[26], rcum[27];
    int tid = threadIdx.x;
    int b   = blockIdx.x >> 9;
    int rid = blockIdx.x & (REG_PER_B - 1);
    int z0 = (rid >> 5) * RZ, y0 = (rid & 31) * RY;

    for (int i = tid; i < RZ*RY*VOL; i += 256) tile[i] = 0.f;

    if (tid < 13) {
        int zr = z0 - 3 + tid;
        int zz = (zr + VOL) & (VOL-1);
        int base = zz * VOL;
        int ylo = y0 - 3, yhi = y0 + RY + 2;
        int a0, a1, b0, b1;
        if (ylo < 0)        { a0 = ylo + VOL; a1 = VOL; b0 = 0; b1 = yhi; }
        else if (yhi > VOL) { a0 = ylo; a1 = VOL; b0 = 0; b1 = yhi - VOL; }
        else                { a0 = ylo; a1 = yhi; b0 = 0; b1 = 0; }
        unsigned sA = binstart[base + a0];
        rstart[tid*2]   = sA;
        rcnt[tid*2]     = binstart[base + a1] - sA;
        unsigned sB = binstart[base + b0];
        rstart[tid*2+1] = sB;
        rcnt[tid*2+1]   = (b1 > b0) ? (binstart[base + b1] - sB) : 0u;
    }
    __syncthreads();
    if (tid == 0) {
        unsigned run = 0;
        #pragma unroll
        for (int r = 0; r < 26; ++r) { rcum[r] = run; run += rcnt[r]; }
        rcum[26] = run;
    }
    __syncthreads();

    const int ox[8] = {0,1,0,0,0,1,1,1};
    const int oy[8] = {0,0,1,0,1,0,1,1};
    const int oz[8] = {0,0,0,1,1,1,0,1};
    const float4* cb = coords_s + (size_t)b * NPTS;

    unsigned total = rcum[26];
    int r = 0;
    for (unsigned f = tid; f < total; f += 1024) {
        // phase 1: address generation (LDS-only cursor walk)
        unsigned j[4]; bool v[4];
        #pragma unroll
        for (int u = 0; u < 4; ++u) {
            unsigned fu = f + (unsigned)u * 256u;
            v[u] = fu < total;
            if (v[u]) {
                while (fu >= rcum[r+1]) ++r;
                j[u] = rstart[r] + (fu - rcum[r]);
            }
        }
        // phase 2: independent global gathers (back-to-back issue)
        float4 c[4]; unsigned kk[4];
        #pragma unroll
        for (int u = 0; u < 4; ++u) {
            if (v[u]) {
                c[u]  = cb[j[u]];
                kk[u] = keys[j[u]];
            }
        }
        // phase 3: process
        #pragma unroll
        for (int u = 0; u < 4; ++u) {
            if (!v[u]) continue;
            int piz = (int)(kk[u] >> 7), piy = (int)(kk[u] & 127u);
            float4 cc = c[u];
            float fxf = floorf(cc.x), fyf = floorf(cc.y), fzf = floorf(cc.z);
            int bx = (int)fxf, by = (int)fyf, bz = (int)fzf;
            bool nearzy = ((unsigned)(bz - piz + 2) <= 4u) &&
                          ((unsigned)(by - piy + 2) <= 4u);
            if (!nearzy) continue;
            float fx = cc.x - fxf, fy = cc.y - fyf, fz = cc.z - fzf;
            float gx = 1.f - fx, gy = 1.f - fy, gz = 1.f - fz;
            float val = cc.w;
            float w[8] = {gx*gy*gz, fx*gy*gz, gx*fy*gz, gx*gy*fz,
                          gx*fy*fz, fx*gy*fz, fx*fy*gz, fx*fy*fz};
            #pragma unroll
            for (int o = 0; o < 8; ++o) {
                int Z = (bz + oz[o]) & 127, dz = Z - z0;
                if ((unsigned)dz >= RZ) continue;
                int Y = (by + oy[o]) & 127, dy = Y - y0;
                if ((unsigned)dy >= RY) continue;
                int X = (bx + ox[o]) & 127;
                atomicAdd(&tile[(dz << 9) + (dy << 7) + X], val * w[o]);
            }
        }
    }
    __syncthreads();
    size_t ob = (size_t)b * V3;
    for (int i = tid; i < RZ*RY*VOL; i += 256) {
        int lz = i >> 9, ly = (i >> 7) & (RY-1), lx = i & 127;
        out[ob + (size_t)(z0+lz)*V2 + (y0+ly)*VOL + lx] = tile[i];
    }
}

// Cleanup for far-displaced entries (expected ~hundreds).
__global__ __launch_bounds__(256) void far_kernel(
    const float4* __restrict__ coords_s, const unsigned* __restrict__ ctrl,
    const unsigned* __restrict__ farlist, float* __restrict__ out)
{
    unsigned cnt = ctrl[0];
    if (cnt > FAR_CAP) cnt = FAR_CAP;
    const int ox[8] = {0,1,0,0,0,1,1,1};
    const int oy[8] = {0,0,1,0,1,0,1,1};
    const int oz[8] = {0,0,0,1,1,1,0,1};
    for (unsigned idx = blockIdx.x * 256 + threadIdx.x; idx < cnt;
         idx += gridDim.x * 256) {
        unsigned e = farlist[idx];
        unsigned pos = e >> 3;
        int b = (int)(e & 7u);
        float4 c = coords_s[(size_t)b * NPTS + pos];
        float fxf = floorf(c.x), fyf = floorf(c.y), fzf = floorf(c.z);
        int bx = (int)fxf, by = (int)fyf, bz = (int)fzf;
        float fx = c.x - fxf, fy = c.y - fyf, fz = c.z - fzf;
        float gx = 1.f - fx, gy = 1.f - fy, gz = 1.f - fz;
        float val = c.w;
        float w[8] = {gx*gy*gz, fx*gy*gz, gx*fy*gz, gx*gy*fz,
                      gx*fy*fz, fx*gy*fz, fx*fy*gz, fx*fy*fz};
        float* ob = out + (size_t)b * V3;
        #pragma unroll
        for (int o = 0; o < 8; ++o) {
            int Z = (bz + oz[o]) & (VOL-1);
            int Y = (by + oy[o]) & (VOL-1);
            int X = (bx + ox[o]) & (VOL-1);
            atomicAdd(ob + (size_t)Z*V2 + Y*VOL + X, val * w[o]);
        }
    }
}

// Fallback (round-11 verified path) if workspace too small.
__global__ __launch_bounds__(256) void scatter_fallback(
    const float* __restrict__ Wf, const float* __restrict__ bfv_g,
    const float* __restrict__ rv, const int* __restrict__ inds,
    const float* __restrict__ hbuf, float* __restrict__ out)
{
    __shared__ float hs[BATCH*8];
    if (threadIdx.x < BATCH*8) hs[threadIdx.x] = hbuf[threadIdx.x];
    __syncthreads();
    int n = blockIdx.x * blockDim.x + threadIdx.x;
    if (n >= NPTS) return;
    int iz = inds[n*3 + 0], iy = inds[n*3 + 1], ix = inds[n*3 + 2];
    float cnx = ((float)ix - FACTORF) / FACTORF;
    float cny = ((float)iy - FACTORF) / FACTORF;
    float cnz = ((float)iz - FACTORF) / FACTORF;
    float val0 = rv[n];
    float4 bfv = ((const float4*)bfv_g)[n];
    float4 wf[8];
    #pragma unroll
    for (int r = 0; r < 8; ++r)
        wf[r] = ((const float4*)(Wf + (size_t)r * 4 * NPTS))[n];
    static const int offs[8][3] = {{0,0,0},{1,0,0},{0,1,0},{0,0,1},
                                   {0,1,1},{1,0,1},{1,1,0},{1,1,1}};
    #pragma unroll
    for (int b = 0; b < BATCH; ++b) {
        float o0 = bfv.x, o1 = bfv.y, o2 = bfv.z, o3 = bfv.w;
        #pragma unroll
        for (int r = 0; r < 8; ++r) {
            float hv = hs[b*8 + r];
            o0 = fmaf(hv, wf[r].x, o0);
            o1 = fmaf(hv, wf[r].y, o1);
            o2 = fmaf(hv, wf[r].z, o2);
            o3 = fmaf(hv, wf[r].w, o3);
        }
        float cx = FACTORF * (cnx + o0) + FACTORF;
        float cy = FACTORF * (cny + o1) + FACTORF;
        float cz = FACTORF * (cnz + o2) + FACTORF;
        float val = val0 + o3;
        float fxf = floorf(cx), fyf = floorf(cy), fzf = floorf(cz);
        int bx = (int)fxf, by = (int)fyf, bz = (int)fzf;
        float fx = cx - fxf, fy = cy - fyf, fz = cz - fzf;
        float gx = 1.f - fx, gy = 1.f - fy, gz = 1.f - fz;
        float w[8] = {gx*gy*gz, fx*gy*gz, gx*fy*gz, gx*gy*fz,
                      gx*fy*fz, fx*gy*fz, fx*fy*gz, fx*fy*fz};
        float* ob = out + (size_t)b * V3;
        #pragma unroll
        for (int o = 0; o < 8; ++o) {
            int X = (bx + offs[o][0]) & (VOL-1);
            int Y = (by + offs[o][1]) & (VOL-1);
            int Z = (bz + offs[o][2]) & (VOL-1);
            atomicAdd(ob + (size_t)Z*V2 + Y*VOL + X, val * w[o]);
        }
    }
}

extern "C" void kernel_launch(void* const* d_in, const int* in_sizes, int n_in,
                              void* d_out, int out_size, void* d_ws, size_t ws_size,
                              hipStream_t stream) {
    const float* x    = (const float*)d_in[0];
    const float* W0   = (const float*)d_in[1];
    const float* b0   = (const float*)d_in[2];
    const float* Wh   = (const float*)d_in[3];
    const float* bh   = (const float*)d_in[4];
    const float* Wf   = (const float*)d_in[5];
    const float* bf   = (const float*)d_in[6];
    const float* rv   = (const float*)d_in[7];
    const int*   inds = (const int*)d_in[8];
    float* out = (float*)d_out;
    char*  ws  = (char*)d_ws;

    float*          hbuf     = (float*)(ws + WS_HBUF);
    unsigned*       hist     = (unsigned*)(ws + WS_HIST);
    unsigned*       binstart = (unsigned*)(ws + WS_START);
    unsigned*       rank     = (unsigned*)(ws + WS_RANK);
    unsigned short* keys     = (unsigned short*)(ws + WS_KEYS);
    unsigned*       ctrl     = (unsigned*)(ws + WS_CTRL);
    unsigned*       wgsum    = (unsigned*)(ws + WS_WGSUM);
    unsigned*       farlist  = (unsigned*)(ws + WS_FARLIST);
    float4*         coords_s = (float4*)(ws + WS_COORDS);

    mlp_kernel<<<1, 64, 0, stream>>>(x, W0, b0, Wh, bh, hbuf);

    if (ws_size >= (size_t)WS_FULL) {
        hipMemsetAsync(hist, 0, NBINS*4, stream);
        hist_rank_kernel<<<NPTS/256, 256, 0, stream>>>(inds, hist, rank);
        scanA_kernel<<<64, 256, 0, stream>>>(hist, wgsum);
        scanB_kernel<<<1, 64, 0, stream>>>(wgsum, binstart, ctrl);
        scanC_kernel<<<64, 256, 0, stream>>>(hist, wgsum, binstart);
        coords_kernel<<<NPTS/256, 256, 0, stream>>>(Wf, bf, rv, inds, hbuf,
                                                    binstart, rank, keys,
                                                    ctrl, farlist, coords_s);
        region_kernel<<<REG_PER_B*BATCH, 256, 0, stream>>>(coords_s, keys,
                                                           binstart, out);
        far_kernel<<<8, 256, 0, stream>>>(coords_s, ctrl, farlist, out);
    } else {
        hipMemsetAsync(d_out, 0, (size_t)out_size * sizeof(float), stream);
        scatter_fallback<<<NPTS/256, 256, 0, stream>>>(Wf, bf, rv, inds, hbuf, out);
    }
}

// Round 25
// 178.600 us; speedup vs baseline: 1.1106x; 1.0048x over previous
//
#include <hip/hip_runtime.h>
#include <math.h>

#define VOL   128
#define V2    (VOL*VOL)
#define V3    (VOL*VOL*VOL)
#define NPTS  262144
#define LATD  16
#define BATCH 8
#define FACTORF 64.0f
#define NBINS (VOL*VOL)
#define RZ 8
#define RY 4
#define REG_PER_B ((VOL/RZ)*(VOL/RY))   // 512
#define FAR_CAP 8128

// ws layout (bytes) -- within the 35.3MB proven available (R16)
#define WS_HBUF    0u
#define WS_HIST    256u
#define WS_START   65792u
#define WS_RANK    131344u
#define WS_KEYS    1179920u
#define WS_CTRL    1704208u
#define WS_WGSUM   1704240u
#define WS_FARLIST 1704496u
#define WS_COORDS  1737008u
#define WS_FULL    35291440u

__device__ __forceinline__ float bf16r(float x) {
    unsigned u = __float_as_uint(x);
    u = (u + 0x7fffu + ((u >> 16) & 1u)) & 0xffff0000u;
    return __uint_as_float(u);
}

// SIREN MLP, per-op bf16 (verified round 11).
__global__ void mlp_kernel(const float* __restrict__ x,
                           const float* __restrict__ W0,
                           const float* __restrict__ b0,
                           const float* __restrict__ Wh,
                           const float* __restrict__ bh,
                           float* __restrict__ hout) {
    int b = threadIdx.x;
    if (b >= BATCH) return;
    float xb[LATD];
    #pragma unroll
    for (int i = 0; i < LATD; ++i) xb[i] = bf16r(x[b*LATD + i]);
    float h[8];
    #pragma unroll
    for (int j = 0; j < 8; ++j) {
        float acc = 0.f;
        #pragma unroll
        for (int i = 0; i < LATD; ++i) acc += xb[i] * bf16r(W0[i*8 + j]);
        float t = bf16r(acc);
        t = bf16r(t + bf16r(b0[j]));
        t = bf16r(30.0f * t);
        h[j] = bf16r(sinf(t));
    }
    for (int l = 0; l < 4; ++l) {
        float nh[8];
        #pragma unroll
        for (int j = 0; j < 8; ++j) {
            float acc = 0.f;
            #pragma unroll
            for (int r = 0; r < 8; ++r) acc += h[r] * bf16r(Wh[(l*8 + r)*8 + j]);
            float t = bf16r(acc);
            t = bf16r(t + bf16r(bh[l*8 + j]));
            float s = bf16r(sinf(t));
            nh[j] = bf16r(h[j] + s);
        }
        #pragma unroll
        for (int j = 0; j < 8; ++j) h[j] = nh[j];
    }
    #pragma unroll
    for (int j = 0; j < 8; ++j) hout[b*8 + j] = h[j];
}

// Histogram of source bins + within-bin rank (fused).
__global__ __launch_bounds__(256) void hist_rank_kernel(const int* __restrict__ inds,
                                                        unsigned* __restrict__ hist,
                                                        unsigned* __restrict__ rank) {
    int n = blockIdx.x * 256 + threadIdx.x;
    if (n >= NPTS) return;
    rank[n] = atomicAdd(&hist[inds[n*3]*VOL + inds[n*3+1]], 1u);
}

// Multi-block scan over 16384 bins.
__global__ __launch_bounds__(256) void scanA_kernel(const unsigned* __restrict__ hist,
                                                    unsigned* __restrict__ wgsum) {
    __shared__ unsigned s[256];
    int t = threadIdx.x;
    s[t] = hist[blockIdx.x * 256 + t];
    __syncthreads();
    for (int off = 128; off > 0; off >>= 1) {
        if (t < off) s[t] += s[t + off];
        __syncthreads();
    }
    if (t == 0) wgsum[blockIdx.x] = s[0];
}
__global__ __launch_bounds__(64) void scanB_kernel(unsigned* __restrict__ wgsum,
                                                   unsigned* __restrict__ binstart,
                                                   unsigned* __restrict__ ctrl) {
    if (threadIdx.x == 0) {
        unsigned run = 0;
        for (int i = 0; i < 64; ++i) { unsigned v = wgsum[i]; wgsum[i] = run; run += v; }
        binstart[NBINS] = run;
        ctrl[0] = 0u; ctrl[1] = 0u;
    }
}
__global__ __launch_bounds__(256) void scanC_kernel(const unsigned* __restrict__ hist,
                                                    const unsigned* __restrict__ wgsum,
                                                    unsigned* __restrict__ binstart) {
    __shared__ unsigned s[256];
    int t = threadIdx.x;
    int idx = blockIdx.x * 256 + t;
    unsigned h = hist[idx];
    s[t] = h; __syncthreads();
    for (int off = 1; off < 256; off <<= 1) {
        unsigned v = (t >= off) ? s[t - off] : 0u;
        __syncthreads();
        s[t] += v;
        __syncthreads();
    }
    binstart[idx] = s[t] - h + wgsum[blockIdx.x];
}

// Per point: coords for all 8 batches into bin-sorted planes; keys; far det.
__global__ __launch_bounds__(256) void coords_kernel(
    const float* __restrict__ Wf, const float* __restrict__ bfv_g,
    const float* __restrict__ rv, const int* __restrict__ inds,
    const float* __restrict__ hbuf, const unsigned* __restrict__ binstart,
    const unsigned* __restrict__ rank, unsigned short* __restrict__ keys,
    unsigned* __restrict__ ctrl, unsigned* __restrict__ farlist,
    float4* __restrict__ coords_s)
{
    __shared__ float hs[64];
    if (threadIdx.x < 64) hs[threadIdx.x] = hbuf[threadIdx.x];
    __syncthreads();
    int n = blockIdx.x * 256 + threadIdx.x;
    if (n >= NPTS) return;
    int iz = inds[n*3], iy = inds[n*3+1], ix = inds[n*3+2];
    float cnx = ((float)ix - FACTORF) / FACTORF;
    float cny = ((float)iy - FACTORF) / FACTORF;
    float cnz = ((float)iz - FACTORF) / FACTORF;
    float val0 = rv[n];
    float4 bfv = ((const float4*)bfv_g)[n];
    float4 wf[8];
    #pragma unroll
    for (int r = 0; r < 8; ++r)
        wf[r] = ((const float4*)(Wf + (size_t)r * 4 * NPTS))[n];
    unsigned pos = binstart[iz*VOL + iy] + rank[n];
    keys[pos] = (unsigned short)((iz << 7) | iy);
    #pragma unroll
    for (int b = 0; b < BATCH; ++b) {
        float o0 = bfv.x, o1 = bfv.y, o2 = bfv.z, o3 = bfv.w;
        #pragma unroll
        for (int r = 0; r < 8; ++r) {
            float hv = hs[b*8 + r];
            o0 = fmaf(hv, wf[r].x, o0);
            o1 = fmaf(hv, wf[r].y, o1);
            o2 = fmaf(hv, wf[r].z, o2);
            o3 = fmaf(hv, wf[r].w, o3);
        }
        float4 c;
        c.x = FACTORF * (cnx + o0) + FACTORF;
        c.y = FACTORF * (cny + o1) + FACTORF;
        c.z = FACTORF * (cnz + o2) + FACTORF;
        c.w = val0 + o3;
        coords_s[(size_t)b * NPTS + pos] = c;
        int bz = (int)floorf(c.z), by = (int)floorf(c.y);
        bool nearzy = ((unsigned)(bz - iz + 2) <= 4u) &&
                      ((unsigned)(by - iy + 2) <= 4u);
        if (!nearzy) {
            unsigned fp = atomicAdd(&ctrl[0], 1u);
            if (fp < FAR_CAP) farlist[fp] = (pos << 3) | (unsigned)b;
        }
    }
}

// One wg = (batch, RZ x RY x 128 region). Window-local lane permutation:
// within each 1024-entry window, lane handles entry w0 + ((tid+u*256)*33
// mod 1024) -- lanes ~33 entries (~2 bins) apart, so one wave-instruction's
// ds_adds hit DIFFERENT tile addresses (no same-address RMW serialization),
// while all accesses stay inside the window's ~18KB (line reuse preserved).
// Per-slot binary search (independent) replaces the serial cursor chain;
// 4 slots keep VGPRs < 64 so the allocator can hold all loads in flight.
__global__ __launch_bounds__(256) void region_kernel(
    const float4* __restrict__ coords_s, const unsigned short* __restrict__ keys,
    const unsigned* __restrict__ binstart, float* __restrict__ out)
{
    __shared__ float tile[RZ*RY*VOL];   // 16 KB
    __shared__ unsigned rstart[26], rcnt[26], rcum[27];
    int tid = threadIdx.x;
    int b   = blockIdx.x >> 9;
    int rid = blockIdx.x & (REG_PER_B - 1);
    int z0 = (rid >> 5) * RZ, y0 = (rid & 31) * RY;

    for (int i = tid; i < RZ*RY*VOL; i += 256) tile[i] = 0.f;

    if (tid < 13) {
        int zr = z0 - 3 + tid;
        int zz = (zr + VOL) & (VOL-1);
        int base = zz * VOL;
        int ylo = y0 - 3, yhi = y0 + RY + 2;
        int a0, a1, b0, b1;
        if (ylo < 0)        { a0 = ylo + VOL; a1 = VOL; b0 = 0; b1 = yhi; }
        else if (yhi > VOL) { a0 = ylo; a1 = VOL; b0 = 0; b1 = yhi - VOL; }
        else                { a0 = ylo; a1 = yhi; b0 = 0; b1 = 0; }
        unsigned sA = binstart[base + a0];
        rstart[tid*2]   = sA;
        rcnt[tid*2]     = binstart[base + a1] - sA;
        unsigned sB = binstart[base + b0];
        rstart[tid*2+1] = sB;
        rcnt[tid*2+1]   = (b1 > b0) ? (binstart[base + b1] - sB) : 0u;
    }
    __syncthreads();
    if (tid == 0) {
        unsigned run = 0;
        #pragma unroll
        for (int r = 0; r < 26; ++r) { rcum[r] = run; run += rcnt[r]; }
        rcum[26] = run;
    }
    __syncthreads();

    const int ox[8] = {0,1,0,0,0,1,1,1};
    const int oy[8] = {0,0,1,0,1,0,1,1};
    const int oz[8] = {0,0,0,1,1,1,0,1};
    const float4* cb = coords_s + (size_t)b * NPTS;

    unsigned total = rcum[26];
    for (unsigned w0 = 0; w0 < total; w0 += 1024u) {
        // phase 1: permuted flat index + independent binary search
        unsigned jj[4]; bool v[4];
        #pragma unroll
        for (int u = 0; u < 4; ++u) {
            unsigned fu = w0 + ((((unsigned)tid + (unsigned)u * 256u) * 33u) & 1023u);
            v[u] = fu < total;
            if (v[u]) {
                int lo = 0, hi = 26;
                while (lo + 1 < hi) {
                    int mid = (lo + hi) >> 1;
                    if (rcum[mid] <= fu) lo = mid; else hi = mid;
                }
                jj[u] = rstart[lo] + (fu - rcum[lo]);
            }
        }
        // phase 2: independent global gathers
        float4 c[4]; unsigned kk[4];
        #pragma unroll
        for (int u = 0; u < 4; ++u) {
            if (v[u]) {
                c[u]  = cb[jj[u]];
                kk[u] = keys[jj[u]];
            }
        }
        // phase 3: process
        #pragma unroll
        for (int u = 0; u < 4; ++u) {
            if (!v[u]) continue;
            int piz = (int)(kk[u] >> 7), piy = (int)(kk[u] & 127u);
            float4 cc = c[u];
            float fxf = floorf(cc.x), fyf = floorf(cc.y), fzf = floorf(cc.z);
            int bx = (int)fxf, by = (int)fyf, bz = (int)fzf;
            bool nearzy = ((unsigned)(bz - piz + 2) <= 4u) &&
                          ((unsigned)(by - piy + 2) <= 4u);
            if (!nearzy) continue;
            float fx = cc.x - fxf, fy = cc.y - fyf, fz = cc.z - fzf;
            float gx = 1.f - fx, gy = 1.f - fy, gz = 1.f - fz;
            float val = cc.w;
            float w[8] = {gx*gy*gz, fx*gy*gz, gx*fy*gz, gx*gy*fz,
                          gx*fy*fz, fx*gy*fz, fx*fy*gz, fx*fy*fz};
            #pragma unroll
            for (int o = 0; o < 8; ++o) {
                int Z = (bz + oz[o]) & 127, dz = Z - z0;
                if ((unsigned)dz >= RZ) continue;
                int Y = (by + oy[o]) & 127, dy = Y - y0;
                if ((unsigned)dy >= RY) continue;
                int X = (bx + ox[o]) & 127;
                atomicAdd(&tile[(dz << 9) + (dy << 7) + X], val * w[o]);
            }
        }
    }
    __syncthreads();
    size_t ob = (size_t)b * V3;
    for (int i = tid; i < RZ*RY*VOL; i += 256) {
        int lz = i >> 9, ly = (i >> 7) & (RY-1), lx = i & 127;
        out[ob + (size_t)(z0+lz)*V2 + (y0+ly)*VOL + lx] = tile[i];
    }
}

// Cleanup for far-displaced entries (expected ~hundreds).
__global__ __launch_bounds__(256) void far_kernel(
    const float4* __restrict__ coords_s, const unsigned* __restrict__ ctrl,
    const unsigned* __restrict__ farlist, float* __restrict__ out)
{
    unsigned cnt = ctrl[0];
    if (cnt > FAR_CAP) cnt = FAR_CAP;
    const int ox[8] = {0,1,0,0,0,1,1,1};
    const int oy[8] = {0,0,1,0,1,0,1,1};
    const int oz[8] = {0,0,0,1,1,1,0,1};
    for (unsigned idx = blockIdx.x * 256 + threadIdx.x; idx < cnt;
         idx += gridDim.x * 256) {
        unsigned e = farlist[idx];
        unsigned pos = e >> 3;
        int b = (int)(e & 7u);
        float4 c = coords_s[(size_t)b * NPTS + pos];
        float fxf = floorf(c.x), fyf = floorf(c.y), fzf = floorf(c.z);
        int bx = (int)fxf, by = (int)fyf, bz = (int)fzf;
        float fx = c.x - fxf, fy = c.y - fyf, fz = c.z - fzf;
        float gx = 1.f - fx, gy = 1.f - fy, gz = 1.f - fz;
        float val = c.w;
        float w[8] = {gx*gy*gz, fx*gy*gz, gx*fy*gz, gx*gy*fz,
                      gx*fy*fz, fx*gy*fz, fx*fy*gz, fx*fy*fz};
        float* ob = out + (size_t)b * V3;
        #pragma unroll
        for (int o = 0; o < 8; ++o) {
            int Z = (bz + oz[o]) & (VOL-1);
            int Y = (by + oy[o]) & (VOL-1);
            int X = (bx + ox[o]) & (VOL-1);
            atomicAdd(ob + (size_t)Z*V2 + Y*VOL + X, val * w[o]);
        }
    }
}

// Fallback (round-11 verified path) if workspace too small.
__global__ __launch_bounds__(256) void scatter_fallback(
    const float* __restrict__ Wf, const float* __restrict__ bfv_g,
    const float* __restrict__ rv, const int* __restrict__ inds,
    const float* __restrict__ hbuf, float* __restrict__ out)
{
    __shared__ float hs[BATCH*8];
    if (threadIdx.x < BATCH*8) hs[threadIdx.x] = hbuf[threadIdx.x];
    __syncthreads();
    int n = blockIdx.x * blockDim.x + threadIdx.x;
    if (n >= NPTS) return;
    int iz = inds[n*3 + 0], iy = inds[n*3 + 1], ix = inds[n*3 + 2];
    float cnx = ((float)ix - FACTORF) / FACTORF;
    float cny = ((float)iy - FACTORF) / FACTORF;
    float cnz = ((float)iz - FACTORF) / FACTORF;
    float val0 = rv[n];
    float4 bfv = ((const float4*)bfv_g)[n];
    float4 wf[8];
    #pragma unroll
    for (int r = 0; r < 8; ++r)
        wf[r] = ((const float4*)(Wf + (size_t)r * 4 * NPTS))[n];
    static const int offs[8][3] = {{0,0,0},{1,0,0},{0,1,0},{0,0,1},
                                   {0,1,1},{1,0,1},{1,1,0},{1,1,1}};
    #pragma unroll
    for (int b = 0; b < BATCH; ++b) {
        float o0 = bfv.x, o1 = bfv.y, o2 = bfv.z, o3 = bfv.w;
        #pragma unroll
        for (int r = 0; r < 8; ++r) {
            float hv = hs[b*8 + r];
            o0 = fmaf(hv, wf[r].x, o0);
            o1 = fmaf(hv, wf[r].y, o1);
            o2 = fmaf(hv, wf[r].z, o2);
            o3 = fmaf(hv, wf[r].w, o3);
        }
        float cx = FACTORF * (cnx + o0) + FACTORF;
        float cy = FACTORF * (cny + o1) + FACTORF;
        float cz = FACTORF * (cnz + o2) + FACTORF;
        float val = val0 + o3;
        float fxf = floorf(cx), fyf = floorf(cy), fzf = floorf(cz);
        int bx = (int)fxf, by = (int)fyf, bz = (int)fzf;
        float fx = cx - fxf, fy = cy - fyf, fz = cz - fzf;
        float gx = 1.f - fx, gy = 1.f - fy, gz = 1.f - fz;
        float w[8] = {gx*gy*gz, fx*gy*gz, gx*fy*gz, gx*gy*fz,
                      gx*fy*fz, fx*gy*fz, fx*fy*gz, fx*fy*fz};
        float* ob = out + (size_t)b * V3;
        #pragma unroll
        for (int o = 0; o < 8; ++o) {
            int X = (bx + offs[o][0]) & (VOL-1);
            int Y = (by + offs[o][1]) & (VOL-1);
            int Z = (bz + offs[o][2]) & (VOL-1);
            atomicAdd(ob + (size_t)Z*V2 + Y*VOL + X, val * w[o]);
        }
    }
}

extern "C" void kernel_launch(void* const* d_in, const int* in_sizes, int n_in,
                              void* d_out, int out_size, void* d_ws, size_t ws_size,
                              hipStream_t stream) {
    const float* x    = (const float*)d_in[0];
    const float* W0   = (const float*)d_in[1];
    const float* b0   = (const float*)d_in[2];
    const float* Wh   = (const float*)d_in[3];
    const float* bh   = (const float*)d_in[4];
    const float* Wf   = (const float*)d_in[5];
    const float* bf   = (const float*)d_in[6];
    const float* rv   = (const float*)d_in[7];
    const int*   inds = (const int*)d_in[8];
    float* out = (float*)d_out;
    char*  ws  = (char*)d_ws;

    float*          hbuf     = (float*)(ws + WS_HBUF);
    unsigned*       hist     = (unsigned*)(ws + WS_HIST);
    unsigned*       binstart = (unsigned*)(ws + WS_START);
    unsigned*       rank     = (unsigned*)(ws + WS_RANK);
    unsigned short* keys     = (unsigned short*)(ws + WS_KEYS);
    unsigned*       ctrl     = (unsigned*)(ws + WS_CTRL);
    unsigned*       wgsum    = (unsigned*)(ws + WS_WGSUM);
    unsigned*       farlist  = (unsigned*)(ws + WS_FARLIST);
    float4*         coords_s = (float4*)(ws + WS_COORDS);

    mlp_kernel<<<1, 64, 0, stream>>>(x, W0, b0, Wh, bh, hbuf);

    if (ws_size >= (size_t)WS_FULL) {
        hipMemsetAsync(hist, 0, NBINS*4, stream);
        hist_rank_kernel<<<NPTS/256, 256, 0, stream>>>(inds, hist, rank);
        scanA_kernel<<<64, 256, 0, stream>>>(hist, wgsum);
        scanB_kernel<<<1, 64, 0, stream>>>(wgsum, binstart, ctrl);
        scanC_kernel<<<64, 256, 0, stream>>>(hist, wgsum, binstart);
        coords_kernel<<<NPTS/256, 256, 0, stream>>>(Wf, bf, rv, inds, hbuf,
                                                    binstart, rank, keys,
                                                    ctrl, farlist, coords_s);
        region_kernel<<<REG_PER_B*BATCH, 256, 0, stream>>>(coords_s, keys,
                                                           binstart, out);
        far_kernel<<<8, 256, 0, stream>>>(coords_s, ctrl, farlist, out);
    } else {
        hipMemsetAsync(d_out, 0, (size_t)out_size * sizeof(float), stream);
        scatter_fallback<<<NPTS/256, 256, 0, stream>>>(Wf, bf, rv, inds, hbuf, out);
    }
}